// Round 2
// baseline (398.286 us; speedup 1.0000x reference)
//
#include <hip/hip_runtime.h>
#include <math.h>
#include <stdint.h>

#define T_DIM 32768
#define TILE 1024
#define BLOCK 256

// ---------- helpers ----------

__device__ __forceinline__ uint32_t float_key(float f) {
    // monotonic mapping float -> uint32 (total order)
    uint32_t u = __float_as_uint(f);
    return (u & 0x80000000u) ? ~u : (u | 0x80000000u);
}

// ---------- kernels ----------

__global__ void init_ws_kernel(uint32_t* ws) { ws[0] = 0u; }

__global__ void max_kernel(const float* __restrict__ x, uint32_t* __restrict__ ws, int n4) {
    int idx = blockIdx.x * blockDim.x + threadIdx.x;
    int stride = gridDim.x * blockDim.x;
    float m = -INFINITY;
    const float4* x4 = reinterpret_cast<const float4*>(x);
    for (int i = idx; i < n4; i += stride) {
        float4 v = x4[i];
        m = fmaxf(m, fmaxf(fmaxf(v.x, v.y), fmaxf(v.z, v.w)));
    }
    // wave (64-lane) butterfly reduce
    #pragma unroll
    for (int off = 32; off > 0; off >>= 1)
        m = fmaxf(m, __shfl_xor(m, off));
    if ((threadIdx.x & 63) == 0)
        atomicMax(ws, float_key(m));
}

__global__ __launch_bounds__(BLOCK) void fused_kernel(
    const float* __restrict__ onset, const float* __restrict__ vel,
    const float* __restrict__ pth, const uint32_t* __restrict__ ws,
    float* __restrict__ probs_out, float* __restrict__ vels_out,
    float w0, float w1, float w2, float w3, float w4, float w5, float w6) {

    __shared__ float sx[TILE + 8];   // onset tile, covers [t0-4, t0+TILE+4)
    __shared__ float sv[TILE + 2];   // vel tile,   covers [t0-1, t0+TILE+1)
    __shared__ float sp[TILE + 2];   // pre-NMS probs, covers [t0-1, t0+TILE+1)

    const int row = blockIdx.y;
    const int t0 = blockIdx.x * TILE;
    const size_t base = (size_t)row * T_DIM;
    const int tid = threadIdx.x;

    // stage onset with reflect padding (numpy 'reflect': no edge repeat)
    for (int i = tid; i < TILE + 8; i += BLOCK) {
        int t = t0 + i - 4;
        if (t < 0) t = -t;
        if (t >= T_DIM) t = 2 * T_DIM - 2 - t;
        sx[i] = onset[base + t];
    }
    // stage velmap with reflect padding
    for (int i = tid; i < TILE + 2; i += BLOCK) {
        int t = t0 + i - 1;
        if (t < 0) t = -t;
        if (t >= T_DIM) t = 2 * T_DIM - 2 - t;
        sv[i] = vel[base + t];
    }
    __syncthreads();

    const bool sel = (ws[0] > 0x80000000u);  // prev_max > 0

    // pre-NMS probs for [t0-1, t0+TILE+1); out-of-range -> -inf (NMS pad)
    for (int i = tid; i < TILE + 2; i += BLOCK) {
        int t = t0 + i - 1;
        float p;
        if (t < 0 || t >= T_DIM) {
            p = -INFINITY;
        } else {
            // blurred[t] = sum_{d=0..6} w[d]*x[reflect(t+d-3)]; taps are sx[i..i+6]
            float acc = __fmul_rn(w0, sx[i]);
            acc = __fadd_rn(acc, __fmul_rn(w1, sx[i + 1]));
            acc = __fadd_rn(acc, __fmul_rn(w2, sx[i + 2]));
            acc = __fadd_rn(acc, __fmul_rn(w3, sx[i + 3]));
            acc = __fadd_rn(acc, __fmul_rn(w4, sx[i + 4]));
            acc = __fadd_rn(acc, __fmul_rn(w5, sx[i + 5]));
            acc = __fadd_rn(acc, __fmul_rn(w6, sx[i + 6]));
            p = sel ? acc : sx[i + 3];  // sx[i+3] == x[t]
        }
        sp[i] = p;
    }
    __syncthreads();

    const float pthresh = pth[0];
    float po[4], vo[4];
    const int j0 = tid * 4;  // output t = t0 + j0 + j
    #pragma unroll
    for (int j = 0; j < 4; ++j) {
        const int i = j0 + j + 1;  // sp index for t
        float p = sp[i];
        float pooled = fmaxf(fmaxf(sp[i - 1], p), sp[i + 1]);
        float o = (p == pooled) ? p : 0.0f;
        o = (o >= pthresh) ? o : 0.0f;
        po[j] = o;
        // vel mean: ((v[t-1]+v[t])+v[t+1]) / 3
        float a = __fadd_rn(__fadd_rn(sv[j0 + j], sv[j0 + j + 1]), sv[j0 + j + 2]);
        float v = __fdiv_rn(a, 3.0f);
        vo[j] = (o > 0.0f) ? v : 0.0f;
    }
    *reinterpret_cast<float4*>(&probs_out[base + t0 + j0]) =
        make_float4(po[0], po[1], po[2], po[3]);
    *reinterpret_cast<float4*>(&vels_out[base + t0 + j0]) =
        make_float4(vo[0], vo[1], vo[2], vo[3]);
}

// ---------- launch ----------

extern "C" void kernel_launch(void* const* d_in, const int* in_sizes, int n_in,
                              void* d_out, int out_size, void* d_ws, size_t ws_size,
                              hipStream_t stream) {
    const float* onset = (const float*)d_in[0];
    const float* vel   = (const float*)d_in[1];
    const float* pth   = (const float*)d_in[2];

    const int n = in_sizes[0];            // B*K*T = 23068672
    const int rows = n / T_DIM;           // 704
    float* probs_out = (float*)d_out;
    float* vels_out  = probs_out + (size_t)n;
    uint32_t* wsu = (uint32_t*)d_ws;

    // Gaussian weights computed on host in f32 semantics matching the
    // reference: exp of exactly-representable args (correctly rounded to
    // f32 via double exp), sequential f32 sum, f32 divide.
    float e[7];
    for (int i = 0; i < 7; ++i) {
        float xi = (float)i - 3.0f;          // exact
        float arg = -0.5f * (xi * xi);       // exact: -4.5,-2,-0.5,0,...
        e[i] = (float)exp((double)arg);      // correctly-rounded f32
    }
    float s = e[0];
    for (int i = 1; i < 7; ++i) s += e[i];   // sequential f32 sum
    float w[7];
    for (int i = 0; i < 7; ++i) w[i] = e[i] / s;

    init_ws_kernel<<<1, 1, 0, stream>>>(wsu);
    max_kernel<<<1024, BLOCK, 0, stream>>>(onset, wsu, n / 4);

    dim3 grid(T_DIM / TILE, rows);
    fused_kernel<<<grid, BLOCK, 0, stream>>>(
        onset, vel, pth, wsu, probs_out, vels_out,
        w[0], w[1], w[2], w[3], w[4], w[5], w[6]);
}

// Round 12
// 331.868 us; speedup vs baseline: 1.2001x; 1.2001x over previous
//
#include <hip/hip_runtime.h>
#include <math.h>
#include <stdint.h>

// Belt: forbid FMA contraction via pragma (may be ignored under
// -ffp-contract=fast per clang semantics — round-10 evidence suggests it was).
#pragma clang fp contract(off)

#define T_DIM 32768
#define BLOCK 256

typedef float v4f __attribute__((ext_vector_type(4)));

// Suspenders: make a float opaque to the backend so mul+add around it can
// NEVER be fused into v_fmac, regardless of -ffp-contract handling. Empty
// asm, zero instructions emitted; pins the blur to separate rte mul/add in
// source order — bitwise-matching the numpy reference chain.
#define FP_BARRIER(x) asm("" : "+v"(x))

// ---------- helpers ----------

__device__ __forceinline__ uint32_t float_key(float f) {
    // monotonic mapping float -> uint32 (total order)
    uint32_t u = __float_as_uint(f);
    return (u & 0x80000000u) ? ~u : (u | 0x80000000u);
}

__device__ __forceinline__ int reflect_idx(int t) {
    // numpy 'reflect' (no edge repeat); valid for |overhang| <= T_DIM-1
    if (t < 0) t = -t;
    if (t >= T_DIM) t = 2 * T_DIM - 2 - t;
    return t;
}

// blurred[t] = sum_{d=0..6} w[d]*taps[d], strict rte mul/add in source order,
// fusion blocked op-by-op.
__device__ __forceinline__ float blur7(const float* __restrict__ w,
                                       const float* taps) {
    float acc = w[0] * taps[0];
    FP_BARRIER(acc);
    #pragma unroll
    for (int d = 1; d < 7; ++d) {
        float p = w[d] * taps[d];
        FP_BARRIER(p);
        acc = acc + p;
        FP_BARRIER(acc);
    }
    return acc;
}

// ---------- kernels ----------

__global__ void init_ws_kernel(uint32_t* ws) { ws[0] = 0u; }

__global__ __launch_bounds__(BLOCK) void max_kernel(const float* __restrict__ x,
                                                    uint32_t* __restrict__ ws, int n4) {
    int idx = blockIdx.x * blockDim.x + threadIdx.x;
    int stride = gridDim.x * blockDim.x;
    float m = -INFINITY;
    const v4f* x4 = reinterpret_cast<const v4f*>(x);
    for (int i = idx; i < n4; i += stride) {
        v4f v = x4[i];
        m = fmaxf(m, fmaxf(fmaxf(v.x, v.y), fmaxf(v.z, v.w)));
    }
    // wave (64-lane) butterfly reduce
    #pragma unroll
    for (int off = 32; off > 0; off >>= 1)
        m = fmaxf(m, __shfl_xor(m, off));
    __shared__ float red[BLOCK / 64];
    if ((threadIdx.x & 63) == 0) red[threadIdx.x >> 6] = m;
    __syncthreads();
    if (threadIdx.x == 0) {
        #pragma unroll
        for (int w = 1; w < BLOCK / 64; ++w) m = fmaxf(m, red[w]);
        atomicMax(ws, float_key(m));  // one atomic per block
    }
}

__global__ __launch_bounds__(BLOCK) void fused_kernel(
    const float* __restrict__ onset, const float* __restrict__ vel,
    const float* __restrict__ pth, const uint32_t* __restrict__ ws,
    float* __restrict__ probs_out, float* __restrict__ vels_out,
    float w0, float w1, float w2, float w3, float w4, float w5, float w6) {

    const int row = blockIdx.y;
    const int j0 = (blockIdx.x * BLOCK + threadIdx.x) * 4;  // 4 outputs per thread
    const size_t base = (size_t)row * T_DIM;

    const bool sel = (ws[0] > 0x80000000u);  // prev_max > 0
    const float pthresh = pth[0];
    const float w[7] = {w0, w1, w2, w3, w4, w5, w6};

    // pb[q] = pre-NMS prob at t = j0+q-1 (q=0..5), -inf outside [0,T)
    // vv[q] = velmap (reflect-padded) at t = j0+q-1
    float pb[6], vv[6];

    if (j0 >= 4 && j0 + 8 <= T_DIM) {
        // ---- fast interior path: 3 overlapping 16B loads per input ----
        const v4f* x4 = reinterpret_cast<const v4f*>(onset + base + j0 - 4);
        v4f A = x4[0], Bv = x4[1], C = x4[2];
        float xx[12] = {A.x, A.y, A.z, A.w, Bv.x, Bv.y, Bv.z, Bv.w, C.x, C.y, C.z, C.w};

        const v4f* v4 = reinterpret_cast<const v4f*>(vel + base + j0 - 4);
        v4f Vm = v4[0], Vc = v4[1], Vp = v4[2];
        vv[0] = Vm.w; vv[1] = Vc.x; vv[2] = Vc.y; vv[3] = Vc.z; vv[4] = Vc.w; vv[5] = Vp.x;

        #pragma unroll
        for (int q = 0; q < 6; ++q) {
            // t = j0+q-1; taps are xx[q .. q+6]
            float acc = blur7(w, &xx[q]);
            pb[q] = sel ? acc : xx[q + 3];  // xx[q+3] == x[t]
        }
    } else {
        // ---- slow edge path (2 threads per row): scalar loads w/ reflect ----
        const float* x = onset + base;
        const float* v = vel + base;
        #pragma unroll
        for (int q = 0; q < 6; ++q) {
            int t = j0 + q - 1;
            vv[q] = v[reflect_idx(t)];
            if (t < 0 || t >= T_DIM) {
                pb[q] = -INFINITY;  // NMS constant pad
            } else {
                float taps[7];
                #pragma unroll
                for (int d = 0; d < 7; ++d)
                    taps[d] = x[reflect_idx(t - 3 + d)];
                float acc = blur7(w, taps);
                pb[q] = sel ? acc : x[t];
            }
        }
    }

    float po[4], vo[4];
    #pragma unroll
    for (int j = 0; j < 4; ++j) {
        float p = pb[j + 1];
        float pooled = fmaxf(fmaxf(pb[j], pb[j + 1]), pb[j + 2]);
        float o = (p == pooled) ? p : 0.0f;
        o = (o >= pthresh) ? o : 0.0f;
        po[j] = o;
        // vel mean: ((v[t-1]+v[t])+v[t+1]) / 3 — adds+div, no mul+add pattern,
        // so no contraction hazard.
        float a = (vv[j] + vv[j + 1]) + vv[j + 2];
        float vmean = a / 3.0f;
        vo[j] = (o > 0.0f) ? vmean : 0.0f;
    }

    // outputs are never re-read: non-temporal stores keep inputs resident in L2/L3
    v4f pov = {po[0], po[1], po[2], po[3]};
    v4f vov = {vo[0], vo[1], vo[2], vo[3]};
    __builtin_nontemporal_store(pov, reinterpret_cast<v4f*>(&probs_out[base + j0]));
    __builtin_nontemporal_store(vov, reinterpret_cast<v4f*>(&vels_out[base + j0]));
}

// ---------- launch ----------

extern "C" void kernel_launch(void* const* d_in, const int* in_sizes, int n_in,
                              void* d_out, int out_size, void* d_ws, size_t ws_size,
                              hipStream_t stream) {
    const float* onset = (const float*)d_in[0];
    const float* vel   = (const float*)d_in[1];
    const float* pth   = (const float*)d_in[2];

    const int n = in_sizes[0];            // B*K*T = 23068672
    const int rows = n / T_DIM;           // 704
    float* probs_out = (float*)d_out;
    float* vels_out  = probs_out + (size_t)n;
    uint32_t* wsu = (uint32_t*)d_ws;

    // Gaussian weights in f32 semantics matching the reference:
    // exp of exactly-representable args (correctly rounded via double exp),
    // sequential f32 sum, f32 divide.
    float e[7];
    for (int i = 0; i < 7; ++i) {
        float xi = (float)i - 3.0f;          // exact
        float arg = -0.5f * (xi * xi);       // exact: -4.5,-2,-0.5,0,...
        e[i] = (float)exp((double)arg);      // correctly-rounded f32
    }
    float s = e[0];
    for (int i = 1; i < 7; ++i) s += e[i];   // sequential f32 sum
    float w[7];
    for (int i = 0; i < 7; ++i) w[i] = e[i] / s;

    init_ws_kernel<<<1, 1, 0, stream>>>(wsu);
    max_kernel<<<1024, BLOCK, 0, stream>>>(onset, wsu, n / 4);

    dim3 grid(T_DIM / (4 * BLOCK), rows);   // (32, 704)
    fused_kernel<<<grid, BLOCK, 0, stream>>>(
        onset, vel, pth, wsu, probs_out, vels_out,
        w[0], w[1], w[2], w[3], w[4], w[5], w[6]);
}